// Round 8
// baseline (11770.470 us; speedup 1.0000x reference)
//
#include <hip/hip_runtime.h>
#include <math.h>

// Problem constants
#define KK     128
#define HH     384
#define H3     1152
#define PP     200
#define LL     50
#define VV     512
#define BB     256
#define II     16
#define NSTEPS 3

#define KP2    132    // keys LDS pitch: bank = (4l+k)%32 -> conflict-free logits
#define NT     576    // 9 waves; 2*NT == H3
#define NC     256    // value threads; each owns columns 2c, 2c+1

#define GH_G16 (HH/16)                 // 24 k-groups of 16 for w_hh
#define PPAD   208                     // prog padded to multiple of 16
#define GI_G16 (PPAD/16)               // 13 k-groups for w_ih
#define WH8_U  (GH_G16 * NT * 2 * 4)   // 110592 uints (442 KB fp8)
#define WI8_U  (GI_G16 * NT * 2 * 4)   // 59904  uints (240 KB fp8)

typedef float floatx2 __attribute__((ext_vector_type(2)));

__device__ __forceinline__ floatx2 cvt_lo(unsigned u) {
    return __builtin_amdgcn_cvt_pk_f32_fp8(u, false);   // bytes 0,1
}
__device__ __forceinline__ floatx2 cvt_hi(unsigned u) {
    return __builtin_amdgcn_cvt_pk_f32_fp8(u, true);    // bytes 2,3
}
__device__ __forceinline__ float rcpf(float x) { return __builtin_amdgcn_rcpf(x); }
__device__ __forceinline__ float sigm(float x) { return rcpf(1.f + __expf(-x)); }
__device__ __forceinline__ float tanh_fast(float x) {
    float xc = fminf(fmaxf(x, -15.f), 15.f);
    float t = __expf(2.f * xc);
    return 1.f - 2.f * rcpf(t + 1.f);
}

// fp8 weight pack. uint index: ((g*NT + t)*2 + s)*4 + m
//   -> row j = 2t+s, k = 16g + 4m + {0..3}  (4 fp8 per uint)
__global__ void pack_weights(const float* __restrict__ w_hh,
                             const float* __restrict__ w_ih,
                             unsigned* __restrict__ ws)
{
    int idx = blockIdx.x * 256 + threadIdx.x;
    if (idx < WH8_U) {
        int g = idx / (NT * 8);
        int r = idx - g * (NT * 8);
        int t = r >> 3, s = (r >> 2) & 1, m = r & 3;
        int j = 2 * t + s, k = 16 * g + 4 * m;
        const float* wr = w_hh + (long)j * HH + k;
        int p = __builtin_amdgcn_cvt_pk_fp8_f32(wr[0], wr[1], 0, false);
        p     = __builtin_amdgcn_cvt_pk_fp8_f32(wr[2], wr[3], p, true);
        ws[idx] = (unsigned)p;
    } else if (idx < WH8_U + WI8_U) {
        int q = idx - WH8_U;
        int g = q / (NT * 8);
        int r = q - g * (NT * 8);
        int t = r >> 3, s = (r >> 2) & 1, m = r & 3;
        int j = 2 * t + s, k = 16 * g + 4 * m;
        float w0 = (k + 0 < PP) ? w_ih[(long)j * PP + k + 0] : 0.f;
        float w1 = (k + 1 < PP) ? w_ih[(long)j * PP + k + 1] : 0.f;
        float w2 = (k + 2 < PP) ? w_ih[(long)j * PP + k + 2] : 0.f;
        float w3 = (k + 3 < PP) ? w_ih[(long)j * PP + k + 3] : 0.f;
        int p = __builtin_amdgcn_cvt_pk_fp8_f32(w0, w1, 0, false);
        p     = __builtin_amdgcn_cvt_pk_fp8_f32(w2, w3, p, true);
        ws[idx] = (unsigned)p;
    }
}

struct __align__(16) Smem {
    float  h[HH];               // f32 h (16B aligned)
    float  prog[PPAD];          // f32 prog, zero-padded
    float2 vals[LL * NC];       // 100 KB; thread c owns cols 2c,2c+1
    float  keys[LL * KP2];      // 26.4 KB
    float  gi[H3];
    float  gh[H3];
    float  ra[LL], wmm[LL], rl[LL], wl[LL], rowoff[LL];
    float  partial[4 * LL];
};  // ~139.5 KB

// 16-k fp8 dot for rows j0 (wa) / j0+1 (wb); short live ranges.
__device__ __forceinline__ void g16(uint4 wa, uint4 wb, const float4* hp4,
                                    float& a0e, float& a0o,
                                    float& a1e, float& a1o)
{
    float4 hm; floatx2 f;
    hm = hp4[0];
    f = cvt_lo(wa.x); a0e = fmaf(f.x, hm.x, a0e); a0o = fmaf(f.y, hm.y, a0o);
    f = cvt_hi(wa.x); a0e = fmaf(f.x, hm.z, a0e); a0o = fmaf(f.y, hm.w, a0o);
    f = cvt_lo(wb.x); a1e = fmaf(f.x, hm.x, a1e); a1o = fmaf(f.y, hm.y, a1o);
    f = cvt_hi(wb.x); a1e = fmaf(f.x, hm.z, a1e); a1o = fmaf(f.y, hm.w, a1o);
    hm = hp4[1];
    f = cvt_lo(wa.y); a0e = fmaf(f.x, hm.x, a0e); a0o = fmaf(f.y, hm.y, a0o);
    f = cvt_hi(wa.y); a0e = fmaf(f.x, hm.z, a0e); a0o = fmaf(f.y, hm.w, a0o);
    f = cvt_lo(wb.y); a1e = fmaf(f.x, hm.x, a1e); a1o = fmaf(f.y, hm.y, a1o);
    f = cvt_hi(wb.y); a1e = fmaf(f.x, hm.z, a1e); a1o = fmaf(f.y, hm.w, a1o);
    hm = hp4[2];
    f = cvt_lo(wa.z); a0e = fmaf(f.x, hm.x, a0e); a0o = fmaf(f.y, hm.y, a0o);
    f = cvt_hi(wa.z); a0e = fmaf(f.x, hm.z, a0e); a0o = fmaf(f.y, hm.w, a0o);
    f = cvt_lo(wb.z); a1e = fmaf(f.x, hm.x, a1e); a1o = fmaf(f.y, hm.y, a1o);
    f = cvt_hi(wb.z); a1e = fmaf(f.x, hm.z, a1e); a1o = fmaf(f.y, hm.w, a1o);
    hm = hp4[3];
    f = cvt_lo(wa.w); a0e = fmaf(f.x, hm.x, a0e); a0o = fmaf(f.y, hm.y, a0o);
    f = cvt_hi(wa.w); a0e = fmaf(f.x, hm.z, a0e); a0o = fmaf(f.y, hm.w, a0o);
    f = cvt_lo(wb.w); a1e = fmaf(f.x, hm.x, a1e); a1o = fmaf(f.y, hm.y, a1o);
    f = cvt_hi(wb.w); a1e = fmaf(f.x, hm.z, a1e); a1o = fmaf(f.y, hm.w, a1o);
}

__global__ __launch_bounds__(NT)
void symop_main(const int* __restrict__ instr,
                const float* __restrict__ gate_emb,
                const float* __restrict__ program_emb,
                const float* __restrict__ primitive_emb,
                const uint4* __restrict__ wT_hh,
                const uint4* __restrict__ wT_ih,
                const float* __restrict__ b_ih,
                const float* __restrict__ b_hh,
                const float* __restrict__ keys_g,
                const float* __restrict__ init_value,
                float* __restrict__ out)
{
    __shared__ Smem sm;

    const int tid  = threadIdx.x;
    const int lane = tid & 63;
    const int wid  = tid >> 6;
    const int b    = blockIdx.x;

    // init
    for (int idx = tid; idx < LL * KK; idx += NT) {
        int l = idx >> 7, k = idx & 127;
        sm.keys[l * KP2 + k] = keys_g[idx];
    }
    float hcur = 0.f;
    if (tid < HH) {
        hcur = keys_g[tid & 127];
        sm.h[tid] = hcur;
    }
    if (tid < NC) {
        float2 iv = *(const float2*)(init_value + 2 * tid);
        for (int l = 0; l < LL; ++l) sm.vals[l * NC + tid] = iv;
    }
    __syncthreads();

    const int j0 = 2 * tid;
    const float2 bh2 = *(const float2*)(b_hh + j0);
    const float2 bi2 = *(const float2*)(b_ih + j0);
    const int ST = NT * 2;   // uint4 stride between k-groups

    for (int i = 0; i < II; ++i) {
        const int word = instr[i * BB + b];
        const float ge0 = gate_emb[2 * word], ge1 = gate_emb[2 * word + 1];
        const float gmx = fmaxf(ge0, ge1);
        const float e0 = __expf(ge0 - gmx), e1 = __expf(ge1 - gmx);
        const float g0 = e0 * rcpf(e0 + e1), g1 = 1.0f - g0;
        float2 prim2 = make_float2(0.f, 0.f);
        if (tid < NC) prim2 = *(const float2*)(primitive_emb + (long)word * VV + 2 * tid);
        const float* pge = program_emb + (long)word * PP;

        if (tid < PPAD) sm.prog[tid] = (tid < PP) ? pge[tid] : 0.f;
        __syncthreads();

        // gi = W_ih @ prog + b_ih — manual 2-deep pipeline, named vars only
        {
            float a0e = bi2.x, a1e = bi2.y, a0o = 0.f, a1o = 0.f;
            const uint4* wp = wT_ih + (size_t)tid * 2;
            uint4 A0 = wp[0],  B0 = wp[1];
            uint4 A1 = wp[ST], B1 = wp[ST + 1];
            #pragma unroll
            for (int g = 0; g < GI_G16; ++g) {
                uint4 nA = A1, nB = B1;
                if (g + 2 < GI_G16) {
                    nA = wp[(size_t)(g + 2) * ST];
                    nB = wp[(size_t)(g + 2) * ST + 1];
                }
                g16(A0, B0, (const float4*)(sm.prog + 16 * g), a0e, a0o, a1e, a1o);
                A0 = A1; B0 = B1; A1 = nA; B1 = nB;
            }
            sm.gi[j0] = a0e + a0o; sm.gi[j0 + 1] = a1e + a1o;
        }
        // gi consumed only after later barriers

        for (int t = 0; t < NSTEPS; ++t) {
            // attention logits: 100 dots of len 128; 4 lanes per dot
            if (tid < 4 * 2 * LL) {
                const int dot = tid >> 2;
                const int sub = tid & 3;
                const int l   = (dot < LL) ? dot : dot - LL;
                const float* p  = (dot < LL) ? (sm.h + KK) : (sm.h + 2 * KK);
                const float* kr = sm.keys + l * KP2;
                float acc = 0.f;
                #pragma unroll
                for (int kk = 0; kk < KK / 4; ++kk) {
                    int k = sub + 4 * kk;
                    acc = fmaf(p[k], kr[k], acc);
                }
                acc += __shfl_xor(acc, 1, 64);
                acc += __shfl_xor(acc, 2, 64);
                if (sub == 0) {
                    if (dot < LL) sm.rl[l] = acc; else sm.wl[l] = acc;
                }
            }
            __syncthreads();

            // wave-level softmax over 50
            if (wid < 2) {
                const float* src = (wid == 0) ? sm.rl : sm.wl;
                float v = (lane < LL) ? src[lane] : -1e30f;
                float m = v;
                #pragma unroll
                for (int mm = 32; mm >= 1; mm >>= 1) m = fmaxf(m, __shfl_xor(m, mm, 64));
                float e = (lane < LL) ? __expf(v - m) : 0.f;
                float s = e;
                #pragma unroll
                for (int mm = 32; mm >= 1; mm >>= 1) s += __shfl_xor(s, mm, 64);
                if (lane < LL) {
                    float r = e * rcpf(s);
                    if (wid == 0) sm.ra[lane] = r;
                    else          sm.wmm[lane] = r;
                }
            }
            __syncthreads();

            // gh = W_hh @ h + b_hh — manual 4-deep pipeline, named vars only
            float a0e = bh2.x, a1e = bh2.y, a0o = 0.f, a1o = 0.f;
            {
                const uint4* wp = wT_hh + (size_t)tid * 2;
                uint4 A0 = wp[0],      B0 = wp[1];
                uint4 A1 = wp[ST],     B1 = wp[ST + 1];
                uint4 A2 = wp[2 * ST], B2 = wp[2 * ST + 1];
                uint4 A3 = wp[3 * ST], B3 = wp[3 * ST + 1];
                #pragma unroll
                for (int g = 0; g < GH_G16; ++g) {
                    uint4 nA = A3, nB = B3;
                    if (g + 4 < GH_G16) {
                        nA = wp[(size_t)(g + 4) * ST];
                        nB = wp[(size_t)(g + 4) * ST + 1];
                    }
                    g16(A0, B0, (const float4*)(sm.h + 16 * g), a0e, a0o, a1e, a1o);
                    A0 = A1; B0 = B1;
                    A1 = A2; B1 = B2;
                    A2 = A3; B2 = B3;
                    A3 = nA; B3 = nB;
                }
            }

            // vals update in LDS: thread c owns columns 2c,2c+1 (under load shadow)
            if (tid < NC) {
                float rv0 = 0.f, rv1 = 0.f;
                #pragma unroll 10
                for (int l = 0; l < LL; ++l) {
                    float2 vv = sm.vals[l * NC + tid];
                    rv0 = fmaf(sm.ra[l], vv.x, rv0);
                    rv1 = fmaf(sm.ra[l], vv.y, rv1);
                }
                const float nv0 = g0 * prim2.x + g1 * rv0;
                const float nv1 = g0 * prim2.y + g1 * rv1;
                #pragma unroll 10
                for (int l = 0; l < LL; ++l) {
                    float2 vv = sm.vals[l * NC + tid];
                    const float w = sm.wmm[l];
                    vv.x = fmaf(w, nv0 - vv.x, vv.x);
                    vv.y = fmaf(w, nv1 - vv.y, vv.y);
                    sm.vals[l * NC + tid] = vv;
                }
            }

            *(float2*)(sm.gh + j0) = make_float2(a0e + a0o, a1e + a1o);
            __syncthreads();

            // GRU pointwise
            if (tid < HH) {
                const int j = tid;
                const float r = sigm(sm.gi[j] + sm.gh[j]);
                const float z = sigm(sm.gi[HH + j] + sm.gh[HH + j]);
                const float n = tanh_fast(sm.gi[2 * HH + j] + r * sm.gh[2 * HH + j]);
                const float hn = (1.f - z) * n + z * hcur;
                hcur = hn;
                sm.h[j] = hn;
            }
            __syncthreads();
        }
    }

    // epilogue: log-sum-exp per row (values bounded ~1 -> no max pass)
    if (tid < NC) {
        #pragma unroll 5
        for (int l = 0; l < LL; ++l) {
            float2 vv = sm.vals[l * NC + tid];
            float e = __expf(vv.x) + __expf(vv.y);
            #pragma unroll
            for (int mm = 32; mm >= 1; mm >>= 1) e += __shfl_xor(e, mm, 64);
            if (lane == 0) sm.partial[wid * LL + l] = e;
        }
    }
    __syncthreads();
    if (tid < LL) {
        float s = 0.f;
        #pragma unroll
        for (int w = 0; w < 4; ++w) s += sm.partial[w * LL + tid];
        sm.rowoff[tid] = logf(s);
    }
    __syncthreads();

    // out[b, v, l]: thread c writes columns 2c and 2c+1
    if (tid < NC) {
        float* ob0 = out + (long)b * VV * LL + (long)(2 * tid) * LL;
        float* ob1 = ob0 + LL;
        #pragma unroll 5
        for (int l = 0; l < LL; l += 2) {
            float2 va = sm.vals[l * NC + tid];
            float2 vb = sm.vals[(l + 1) * NC + tid];
            float o0 = sm.rowoff[l], o1 = sm.rowoff[l + 1];
            *(float2*)(ob0 + l) = make_float2(va.x - o0, vb.x - o1);
            *(float2*)(ob1 + l) = make_float2(va.y - o0, vb.y - o1);
        }
    }
}

__global__ void ta_copy(const int* __restrict__ ta, float* __restrict__ out2)
{
    int idx = blockIdx.x * 256 + threadIdx.x;
    if (idx < BB * LL) {
        int b2 = idx / LL, l = idx % LL;
        out2[idx] = (float)ta[l * BB + b2];
    }
}

extern "C" void kernel_launch(void* const* d_in, const int* in_sizes, int n_in,
                              void* d_out, int out_size, void* d_ws, size_t ws_size,
                              hipStream_t stream)
{
    const int*   instr        = (const int*)  d_in[0];
    const int*   true_actions = (const int*)  d_in[1];
    const float* gate_emb     = (const float*)d_in[2];
    const float* program_emb  = (const float*)d_in[3];
    const float* primitive_emb= (const float*)d_in[4];
    const float* w_ih         = (const float*)d_in[5];
    const float* w_hh         = (const float*)d_in[6];
    const float* b_ih         = (const float*)d_in[7];
    const float* b_hh         = (const float*)d_in[8];
    const float* scratch_keys = (const float*)d_in[9];
    const float* init_value   = (const float*)d_in[10];

    unsigned* wt = (unsigned*)d_ws;                 // 682 KB of ws
    const uint4* wT_hh = (const uint4*)wt;
    const uint4* wT_ih = (const uint4*)(wt + WH8_U);

    {
        int total = WH8_U + WI8_U;
        pack_weights<<<(total + 255) / 256, 256, 0, stream>>>(w_hh, w_ih, wt);
    }

    float* out = (float*)d_out;
    float* out_actions = out;
    float* out_ta      = out + (long)BB * VV * LL;

    symop_main<<<BB, NT, 0, stream>>>(instr, gate_emb, program_emb, primitive_emb,
                                      wT_hh, wT_ih, b_ih, b_hh,
                                      scratch_keys, init_value, out_actions);

    ta_copy<<<(BB * LL + 255) / 256, 256, 0, stream>>>(true_actions, out_ta);
}

// Round 9
// 565.137 us; speedup vs baseline: 20.8276x; 20.8276x over previous
//
#include <hip/hip_runtime.h>
#include <math.h>

// Problem constants
#define KK     128
#define HH     384
#define H3     1152
#define PP     200
#define LL     50
#define VV     512
#define BB     256
#define II     16
#define NSTEPS 3

#define KP     129    // keys LDS pitch (f32)
#define NT     576    // 9 waves; 2*NT == H3

#define GH_O   (HH/8)            // 48 k-octets for w_hh
#define GI_O   (PP/8)            // 25 k-octets for w_ih
#define WH_U   (GH_O * NT * 8)   // 221184 uints (884 KB)
#define WI_U   (GI_O * NT * 8)   // 115200 uints (460 KB)

typedef _Float16 half2v __attribute__((ext_vector_type(2)));
union uhcvt { unsigned u; half2v h; };

__device__ __forceinline__ float dot2(unsigned a, unsigned b, float c) {
    uhcvt x, y; x.u = a; y.u = b;
    return __builtin_amdgcn_fdot2(x.h, y.h, c, false);
}
__device__ __forceinline__ unsigned packh2(float a, float b) {
    uhcvt u; u.h.x = (_Float16)a; u.h.y = (_Float16)b; return u.u;
}
__device__ __forceinline__ float rcpf(float x) { return __builtin_amdgcn_rcpf(x); }
__device__ __forceinline__ float sigm(float x) { return rcpf(1.f + __expf(-x)); }
__device__ __forceinline__ float tanh_fast(float x) {
    float xc = fminf(fmaxf(x, -15.f), 15.f);
    float t = __expf(2.f * xc);
    return 1.f - 2.f * rcpf(t + 1.f);
}

// Weight pack (f16 half2 along k):
// uint index: ((g*NT + t)*2 + s)*4 + m  ->  j = 2t+s, k = 8g+2m (+1 in .y)
__global__ void pack_weights(const float* __restrict__ w_hh,
                             const float* __restrict__ w_ih,
                             unsigned* __restrict__ ws)
{
    int idx = blockIdx.x * 256 + threadIdx.x;
    if (idx < WH_U) {
        int g = idx / (NT * 8);
        int r = idx - g * (NT * 8);
        int t = r >> 3, s = (r >> 2) & 1, m = r & 3;
        int j = 2 * t + s, k = 8 * g + 2 * m;
        ws[idx] = packh2(w_hh[(long)j * HH + k], w_hh[(long)j * HH + k + 1]);
    } else if (idx < WH_U + WI_U) {
        int q = idx - WH_U;
        int g = q / (NT * 8);
        int r = q - g * (NT * 8);
        int t = r >> 3, s = (r >> 2) & 1, m = r & 3;
        int j = 2 * t + s, k = 8 * g + 2 * m;
        ws[idx] = packh2(w_ih[(long)j * PP + k], w_ih[(long)j * PP + k + 1]);
    }
}

struct Smem {
    unsigned hpk[HH / 2];     // 192 uints, 16B-aligned
    unsigned progpk[104];     // 100 used, padded for 16B alignment
    float h[HH];              // f32 h (logits)
    float keys[LL * KP];
    float gi[H3];
    float gh[H3];
    float ra[LL], wmm[LL], rl[LL], wl[LL], rowoff[LL];
    float partial[8 * LL];
};  // ~41 KB

__global__ __launch_bounds__(NT, 3)   // min 3 waves/EU -> VGPR budget ~170
void symop_main(const int* __restrict__ instr,
                const float* __restrict__ gate_emb,
                const float* __restrict__ program_emb,
                const float* __restrict__ primitive_emb,
                const uint4* __restrict__ wT_hh,
                const uint4* __restrict__ wT_ih,
                const float* __restrict__ b_ih,
                const float* __restrict__ b_hh,
                const float* __restrict__ keys_g,
                const float* __restrict__ init_value,
                float* __restrict__ out)
{
    __shared__ Smem sm;

    const int tid  = threadIdx.x;
    const int lane = tid & 63;
    const int wid  = tid >> 6;
    const int b    = blockIdx.x;

    // init
    for (int idx = tid; idx < LL * KK; idx += NT) {
        int l = idx >> 7, k = idx & 127;
        sm.keys[l * KP + k] = keys_g[idx];
    }
    float hcur = 0.f;
    if (tid < HH) {
        hcur = keys_g[tid & 127];
        sm.h[tid] = hcur;
    }
    if (tid < HH / 2)
        sm.hpk[tid] = packh2(keys_g[(2 * tid) & 127], keys_g[(2 * tid + 1) & 127]);

    float vreg[LL];
    if (tid < VV) {
        const float iv = init_value[tid];
        #pragma unroll
        for (int l = 0; l < LL; ++l) vreg[l] = iv;
    }
    __syncthreads();

    const int j0 = 2 * tid;
    const float2 bh2 = *(const float2*)(b_hh + j0);
    const float2 bi2 = *(const float2*)(b_ih + j0);

    for (int i = 0; i < II; ++i) {
        const int word = instr[i * BB + b];
        const float ge0 = gate_emb[2 * word], ge1 = gate_emb[2 * word + 1];
        const float gmx = fmaxf(ge0, ge1);
        const float e0 = __expf(ge0 - gmx), e1 = __expf(ge1 - gmx);
        const float g0 = e0 * rcpf(e0 + e1), g1 = 1.0f - g0;
        const float primv = (tid < VV) ? primitive_emb[(long)word * VV + tid] : 0.f;
        const float* pge = program_emb + (long)word * PP;

        if (tid < PP / 2) {
            float2 pg = *(const float2*)(pge + 2 * tid);
            sm.progpk[tid] = packh2(pg.x, pg.y);
        }
        __syncthreads();

        // gi = W_ih @ prog + b_ih  (dot2, thread owns j0,j0+1)
        {
            float a0 = bi2.x, a1 = bi2.y;
            const uint4* wp = wT_ih + (size_t)tid * 2;
            #pragma unroll 5
            for (int g = 0; g < GI_O; ++g) {
                uint4 wa = wp[(size_t)g * (NT * 2)];
                uint4 wb = wp[(size_t)g * (NT * 2) + 1];
                uint4 hp = *(const uint4*)(sm.progpk + 4 * g);
                a0 = dot2(wa.x, hp.x, a0); a0 = dot2(wa.y, hp.y, a0);
                a0 = dot2(wa.z, hp.z, a0); a0 = dot2(wa.w, hp.w, a0);
                a1 = dot2(wb.x, hp.x, a1); a1 = dot2(wb.y, hp.y, a1);
                a1 = dot2(wb.z, hp.z, a1); a1 = dot2(wb.w, hp.w, a1);
            }
            sm.gi[j0] = a0; sm.gi[j0 + 1] = a1;
        }
        // gi consumed only after later barriers

        for (int t = 0; t < NSTEPS; ++t) {
            // attention logits: 100 dots of len 128; 4 lanes per dot (f32)
            if (tid < 4 * 2 * LL) {
                const int dot = tid >> 2;
                const int sub = tid & 3;
                const int l   = (dot < LL) ? dot : dot - LL;
                const float* p  = (dot < LL) ? (sm.h + KK) : (sm.h + 2 * KK);
                const float* kr = sm.keys + l * KP;
                float acc = 0.f;
                #pragma unroll
                for (int kk = 0; kk < KK / 4; ++kk) {
                    int k = sub + 4 * kk;
                    acc = fmaf(p[k], kr[k], acc);
                }
                acc += __shfl_xor(acc, 1, 64);
                acc += __shfl_xor(acc, 2, 64);
                if (sub == 0) {
                    if (dot < LL) sm.rl[l] = acc; else sm.wl[l] = acc;
                }
            }
            __syncthreads();

            // wave-level softmax over 50
            if (wid < 2) {
                const float* src = (wid == 0) ? sm.rl : sm.wl;
                float v = (lane < LL) ? src[lane] : -1e30f;
                float m = v;
                #pragma unroll
                for (int mm = 32; mm >= 1; mm >>= 1) m = fmaxf(m, __shfl_xor(m, mm, 64));
                float e = (lane < LL) ? __expf(v - m) : 0.f;
                float s = e;
                #pragma unroll
                for (int mm = 32; mm >= 1; mm >>= 1) s += __shfl_xor(s, mm, 64);
                if (lane < LL) {
                    float r = e * rcpf(s);
                    if (wid == 0) sm.ra[lane] = r;
                    else          sm.wmm[lane] = r;
                }
            }
            __syncthreads();

            // gh = W_hh @ h + b_hh (dot2 on packed f16 h; reads hpk — barrier-safe)
            {
                float a0 = bh2.x, a1 = bh2.y;
                const uint4* wp = wT_hh + (size_t)tid * 2;
                #pragma unroll 8
                for (int g = 0; g < GH_O; ++g) {
                    uint4 wa = wp[(size_t)g * (NT * 2)];
                    uint4 wb = wp[(size_t)g * (NT * 2) + 1];
                    uint4 hp = *(const uint4*)(sm.hpk + 4 * g);
                    a0 = dot2(wa.x, hp.x, a0); a0 = dot2(wa.y, hp.y, a0);
                    a0 = dot2(wa.z, hp.z, a0); a0 = dot2(wa.w, hp.w, a0);
                    a1 = dot2(wb.x, hp.x, a1); a1 = dot2(wb.y, hp.y, a1);
                    a1 = dot2(wb.z, hp.z, a1); a1 = dot2(wb.w, hp.w, a1);
                }
                sm.gh[j0] = a0; sm.gh[j0 + 1] = a1;
            }

            // read_value + vals update — pure register FMAs
            if (tid < VV) {
                float rv0 = 0.f, rv1 = 0.f;
                #pragma unroll
                for (int l = 0; l < LL; l += 2) {
                    rv0 = fmaf(sm.ra[l],     vreg[l],     rv0);
                    rv1 = fmaf(sm.ra[l + 1], vreg[l + 1], rv1);
                }
                const float nv = g0 * primv + g1 * (rv0 + rv1);
                #pragma unroll
                for (int l = 0; l < LL; ++l)
                    vreg[l] = fmaf(sm.wmm[l], nv - vreg[l], vreg[l]);
            }
            __syncthreads();

            // GRU pointwise; update register h, f32 LDS h, packed f16 h
            if (tid < HH) {
                const int j = tid;
                const float r = sigm(sm.gi[j] + sm.gh[j]);
                const float z = sigm(sm.gi[HH + j] + sm.gh[HH + j]);
                const float n = tanh_fast(sm.gi[2 * HH + j] + r * sm.gh[2 * HH + j]);
                const float hn = (1.f - z) * n + z * hcur;
                hcur = hn;
                sm.h[j] = hn;
                const float hnb = __shfl_down(hn, 1, 64);
                if (!(tid & 1)) sm.hpk[tid >> 1] = packh2(hn, hnb);
            }
            __syncthreads();
        }
    }

    // epilogue: log-sum-exp per row (values bounded ~1 -> no max pass)
    if (tid < VV) {
        #pragma unroll
        for (int l = 0; l < LL; ++l) {
            float e = __expf(vreg[l]);
            #pragma unroll
            for (int mm = 32; mm >= 1; mm >>= 1) e += __shfl_xor(e, mm, 64);
            if (lane == 0) sm.partial[wid * LL + l] = e;
        }
    }
    __syncthreads();
    if (tid < LL) {
        float s = 0.f;
        #pragma unroll
        for (int w = 0; w < 8; ++w) s += sm.partial[w * LL + tid];
        sm.rowoff[tid] = logf(s);
    }
    __syncthreads();

    // out[b, v, l] = vreg[l] - rowoff[l]; thread v writes 50 contiguous floats
    if (tid < VV) {
        float* ob = out + (long)b * VV * LL + (long)tid * LL;
        #pragma unroll
        for (int l = 0; l < LL; l += 2) {
            float2 w2;
            w2.x = vreg[l]     - sm.rowoff[l];
            w2.y = vreg[l + 1] - sm.rowoff[l + 1];
            *(float2*)(ob + l) = w2;
        }
    }
}

__global__ void ta_copy(const int* __restrict__ ta, float* __restrict__ out2)
{
    int idx = blockIdx.x * 256 + threadIdx.x;
    if (idx < BB * LL) {
        int b2 = idx / LL, l = idx % LL;
        out2[idx] = (float)ta[l * BB + b2];
    }
}

extern "C" void kernel_launch(void* const* d_in, const int* in_sizes, int n_in,
                              void* d_out, int out_size, void* d_ws, size_t ws_size,
                              hipStream_t stream)
{
    const int*   instr        = (const int*)  d_in[0];
    const int*   true_actions = (const int*)  d_in[1];
    const float* gate_emb     = (const float*)d_in[2];
    const float* program_emb  = (const float*)d_in[3];
    const float* primitive_emb= (const float*)d_in[4];
    const float* w_ih         = (const float*)d_in[5];
    const float* w_hh         = (const float*)d_in[6];
    const float* b_ih         = (const float*)d_in[7];
    const float* b_hh         = (const float*)d_in[8];
    const float* scratch_keys = (const float*)d_in[9];
    const float* init_value   = (const float*)d_in[10];

    unsigned* wt = (unsigned*)d_ws;                 // 1.35 MB of ws
    const uint4* wT_hh = (const uint4*)wt;
    const uint4* wT_ih = (const uint4*)(wt + WH_U);

    {
        int total = WH_U + WI_U;
        pack_weights<<<(total + 255) / 256, 256, 0, stream>>>(w_hh, w_ih, wt);
    }

    float* out = (float*)d_out;
    float* out_actions = out;
    float* out_ta      = out + (long)BB * VV * LL;

    symop_main<<<BB, NT, 0, stream>>>(instr, gate_emb, program_emb, primitive_emb,
                                      wT_hh, wT_ih, b_ih, b_hh,
                                      scratch_keys, init_value, out_actions);

    ta_copy<<<(BB * LL + 255) / 256, 256, 0, stream>>>(true_actions, out_ta);
}